// Round 17
// baseline (201.627 us; speedup 1.0000x reference)
//
#include <hip/hip_runtime.h>
#include <math.h>
#include <float.h>
#include <stdint.h>

// NearestNeighborRatio: desc1/desc2 (B=16384, D=128) f32.
// d2(i,j) = |a_i|^2 + |b_j|^2 - 2 a_i.b_j; per-row top-2, ratio = sqrt(d0/d1), mask = ratio<=0.8.
// f16 hi/lo split (x = hi + lo): dot via 3 MFMAs (hh + hl + lh) in fp32 acc.
// v17: v12 per-wave body unchanged; block = 2 waves (128 thr, BM=128) so each CU hosts
//      4 INDEPENDENT barrier groups (was 2) -> phase-decorrelated MFMA/fold/LDS overlap.
//      XCD-aware decode (cspl = bid&7) pins each 1MB B-strip into one XCD's L2.
// Out (flat f32): [0,B) match_dists ; [B,3B) matches_idxs as floats ; [3B,4B) mask 0/1.

typedef __attribute__((ext_vector_type(4))) float     f32x4;
typedef __attribute__((ext_vector_type(8))) _Float16  half8;

#define D_     128
#define BM_    128   // rows per block (2 waves x 64)
#define BN_    32    // cols per iter (= one packed tile)
#define CS_    8     // column splits
#define PARTS_ 8     // partials per row = CS_

__device__ __forceinline__ void gload_lds16(const void* g, void* l) {
  auto gp = (const __attribute__((address_space(1))) unsigned int*)(uintptr_t)g;
  auto lp = (__attribute__((address_space(3))) unsigned int*)(uintptr_t)l;
  __builtin_amdgcn_global_load_lds(gp, lp, 16, 0, 0);
}

__global__ void norms_kernel(const float* __restrict__ d1,
                             const float* __restrict__ d2,
                             float* __restrict__ sq, int B) {
  int gid  = blockIdx.x * blockDim.x + threadIdx.x;
  int wid  = gid >> 6;
  int lane = gid & 63;
  if (wid >= 2 * B) return;
  const float* src = (wid < B) ? (d1 + (size_t)wid * D_)
                               : (d2 + (size_t)(wid - B) * D_);
  float2 v = ((const float2*)src)[lane];
  float s = fmaf(v.x, v.x, v.y * v.y);
  #pragma unroll
  for (int off = 32; off > 0; off >>= 1) s += __shfl_down(s, off, 64);
  if (lane == 0) sq[wid] = s;
}

// A planes: row-major [B][128] f16 (unscaled).
// B planes: packed fragment order per 32-col tile, PRE-SCALED BY -2:
//   f16 offset = t*4096 + kk*1024 + nf*512 + g*128 + c15*8
//   holds -2*desc2[t*32 + nf*16 + c15][kk*32 + g*8 .. +8]
__global__ void convert_kernel(const float* __restrict__ d1, const float* __restrict__ d2,
                               _Float16* __restrict__ Ahi, _Float16* __restrict__ Alo,
                               _Float16* __restrict__ BhiP, _Float16* __restrict__ BloP,
                               int B) {
  int i = blockIdx.x * blockDim.x + threadIdx.x;
  int total = B * 16;                       // 8-elem groups per matrix
  if (i >= 2 * total) return;
  bool isB = i >= total;
  int j    = isB ? i - total : i;
  int desc = j >> 4;
  int seg  = j & 15;                        // 8-f32 group within the row
  const float* src = (isB ? d2 : d1) + (size_t)desc * D_ + seg * 8;
  float4 v0 = *(const float4*)(src);
  float4 v1 = *(const float4*)(src + 4);
  half8 hv, lv;
  float e[8] = {v0.x, v0.y, v0.z, v0.w, v1.x, v1.y, v1.z, v1.w};
  #pragma unroll
  for (int q = 0; q < 8; ++q) {
    _Float16 h = (_Float16)e[q];
    _Float16 l = (_Float16)(e[q] - (float)h);
    if (isB) { h = (_Float16)(-2.0f) * h; l = (_Float16)(-2.0f) * l; }
    hv[q] = h; lv[q] = l;
  }
  if (!isB) {
    *(half8*)(Ahi + (size_t)desc * D_ + seg * 8) = hv;
    *(half8*)(Alo + (size_t)desc * D_ + seg * 8) = lv;
  } else {
    int t   = desc >> 5, cloc = desc & 31;
    int nf  = cloc >> 4, c15  = cloc & 15;
    int kk  = seg >> 2,  gq   = seg & 3;
    size_t off = (size_t)t * 4096 + kk * 1024 + nf * 512 + gq * 128 + c15 * 8;
    *(half8*)(BhiP + off) = hv;
    *(half8*)(BloP + off) = lv;
  }
}

// LDS (dynamic 32KB): buf0 [0,16K), buf1 [16K,32K).
// Within a buf: [0,8K) hi plane, [8K,16K) lo plane; chunk (kk,nf) at kk*2048+nf*1024,
// lane's half8 at +lane*16 (fragment-linear -> zero bank conflicts).
__global__ __launch_bounds__(128, 2)
void nn_mfma(const _Float16* __restrict__ Ahi, const _Float16* __restrict__ Alo,
             const _Float16* __restrict__ BhiP, const _Float16* __restrict__ BloP,
             const float* __restrict__ sqb,
             float* __restrict__ p_d0, float* __restrict__ p_d1,
             int* __restrict__ p_j0, int B) {
  extern __shared__ char smem[];
  const int tid  = threadIdx.x;
  const int lane = tid & 63;
  const int wid  = tid >> 6;       // wave row-group (0,1): rows wid*64..wid*64+63
  const int l15  = lane & 15;
  const int g    = lane >> 4;

  const int bid   = blockIdx.x;
  const int cspl  = bid & 7;            // same strip -> same XCD (round-robin dispatch)
  const int rb    = bid >> 3;           // 0..127
  const int i0    = rb * BM_;
  const int niter = (B / CS_) / BN_;    // 64
  const int tile0 = cspl * niter;

  // ---- A fragments -> registers, once (64 rows per wave: mf=0..3) ----
  half8 ah[4][4], al[4][4];
  #pragma unroll
  for (int mf = 0; mf < 4; ++mf) {
    int row = i0 + wid * 64 + mf * 16 + l15;
    const _Float16* pa = Ahi + (size_t)row * D_ + g * 8;
    const _Float16* pl = Alo + (size_t)row * D_ + g * 8;
    #pragma unroll
    for (int kk = 0; kk < 4; ++kk) {
      ah[mf][kk] = *(const half8*)(pa + kk * 32);
      al[mf][kk] = *(const half8*)(pl + kk * 32);
    }
  }

  // ---- staging: 16 x 1KB chunks per tile; wave wid stages plane wid (8 chunks) ----
  const _Float16* srcW = ((wid == 0) ? BhiP : BloP)
                       + (size_t)tile0 * 4096 + lane * 8;
  char* ldsW = smem + wid * 8192;           // + bufbase
  auto stage = [&](int bufbase, int it) {
    const _Float16* s = srcW + (size_t)it * 4096;
    char* l = ldsW + bufbase;
    #pragma unroll
    for (int e = 0; e < 8; ++e) gload_lds16(s + e * 512, l + e * 1024);
  };

  float best0[16], best1[16]; int bj[16];
  #pragma unroll
  for (int s = 0; s < 16; ++s) { best0[s] = FLT_MAX; best1[s] = FLT_MAX; bj[s] = 0x7fffffff; }

  float sjA[2], sjB[2];
  const int colg0 = tile0 * BN_ + l15;

  // ---- prologue: stage tile 0 into buf0; prefetch sj for it=0 ----
  stage(0, 0);
  #pragma unroll
  for (int nf = 0; nf < 2; ++nf) sjA[nf] = sqb[colg0 + nf * 16];
  __syncthreads();

  auto body = [&](int it, int bufbase, float (&sjc)[2], float (&sjn)[2]) {
    // stage next tile into the other buffer (safe: barrier at end of prev iter)
    if (it + 1 < niter) {
      stage(bufbase ^ 16384, it + 1);
      #pragma unroll
      for (int nf = 0; nf < 2; ++nf) sjn[nf] = sqb[colg0 + (it + 1) * BN_ + nf * 16];
    }

    f32x4 acc[4][2];
    __builtin_amdgcn_s_setprio(1);
    #pragma unroll
    for (int kk = 0; kk < 4; ++kk) {
      half8 bh[2], bl[2];
      #pragma unroll
      for (int nf = 0; nf < 2; ++nf) {
        bh[nf] = *(const half8*)(smem + bufbase + kk * 2048 + nf * 1024 + lane * 16);
        bl[nf] = *(const half8*)(smem + bufbase + 8192 + kk * 2048 + nf * 1024 + lane * 16);
      }
      // term hh (C-init with sj at kk==0)
      #pragma unroll
      for (int mf = 0; mf < 4; ++mf)
        #pragma unroll
        for (int nf = 0; nf < 2; ++nf) {
          if (kk == 0) {
            f32x4 c0 = {sjc[nf], sjc[nf], sjc[nf], sjc[nf]};
            acc[mf][nf] = __builtin_amdgcn_mfma_f32_16x16x32_f16(ah[mf][0], bh[nf], c0, 0, 0, 0);
          } else {
            acc[mf][nf] = __builtin_amdgcn_mfma_f32_16x16x32_f16(ah[mf][kk], bh[nf], acc[mf][nf], 0, 0, 0);
          }
        }
      // term hl
      #pragma unroll
      for (int mf = 0; mf < 4; ++mf)
        #pragma unroll
        for (int nf = 0; nf < 2; ++nf)
          acc[mf][nf] = __builtin_amdgcn_mfma_f32_16x16x32_f16(ah[mf][kk], bl[nf], acc[mf][nf], 0, 0, 0);
      // term lh
      #pragma unroll
      for (int mf = 0; mf < 4; ++mf)
        #pragma unroll
        for (int nf = 0; nf < 2; ++nf)
          acc[mf][nf] = __builtin_amdgcn_mfma_f32_16x16x32_f16(al[mf][kk], bh[nf], acc[mf][nf], 0, 0, 0);
    }
    __builtin_amdgcn_s_setprio(0);

    // ---- top-2 fold (fmed3, 4 VALU/elem); acc[r] = sqb[j] - 2*dot already ----
    // C/D layout: col = lane&15, row = (lane>>4)*4 + reg
    #pragma unroll
    for (int nf = 0; nf < 2; ++nf) {
      int colg = colg0 + it * BN_ + nf * 16;
      #pragma unroll
      for (int mf = 0; mf < 4; ++mf)
        #pragma unroll
        for (int r = 0; r < 4; ++r) {
          int s = mf * 4 + r;
          float t = acc[mf][nf][r];
          best1[s] = __builtin_amdgcn_fmed3f(t, best0[s], best1[s]);
          bool lt0 = t < best0[s];
          best0[s] = fminf(t, best0[s]);
          bj[s]    = lt0 ? colg : bj[s];
        }
    }
    __syncthreads();   // next buffer staged & visible; this buffer free for overwrite
  };

  for (int itp = 0; itp < niter; itp += 2) {
    body(itp,     0,     sjA, sjB);
    body(itp + 1, 16384, sjB, sjA);
  }

  // ---- merge across the 16 col-lanes (same g), index tie-break ----
  #pragma unroll
  for (int off = 1; off < 16; off <<= 1) {
    #pragma unroll
    for (int s = 0; s < 16; ++s) {
      float e0 = __shfl_xor(best0[s], off, 64);
      float e1 = __shfl_xor(best1[s], off, 64);
      int   f0 = __shfl_xor(bj[s],    off, 64);
      if (e0 < best0[s] || (e0 == best0[s] && f0 < bj[s])) {
        best1[s] = fminf(best0[s], e1);
        best0[s] = e0;
        bj[s]    = f0;
      } else {
        best1[s] = fminf(best1[s], e0);
      }
    }
  }

  if (l15 == 0) {
    #pragma unroll
    for (int s = 0; s < 16; ++s) {
      int mf = s >> 2, r = s & 3;
      int row = i0 + wid * 64 + mf * 16 + g * 4 + r;
      p_d0[row * PARTS_ + cspl] = best0[s];
      p_d1[row * PARTS_ + cspl] = best1[s];
      p_j0[row * PARTS_ + cspl] = bj[s];
    }
  }
}

__global__ void nn_final(const float* __restrict__ sqa,
                         const float* __restrict__ p_d0,
                         const float* __restrict__ p_d1,
                         const int* __restrict__ p_j0,
                         float* __restrict__ out, int B) {
  int row = blockIdx.x * blockDim.x + threadIdx.x;
  if (row >= B) return;
  float d0 = FLT_MAX, d1 = FLT_MAX;
  int j0 = 0x7fffffff;
  for (int cs = 0; cs < PARTS_; ++cs) {
    float e0 = p_d0[row * PARTS_ + cs];
    float e1 = p_d1[row * PARTS_ + cs];
    int   f0 = p_j0[row * PARTS_ + cs];
    if (e0 < d0 || (e0 == d0 && f0 < j0)) {
      d1 = fminf(d0, e1);
      d0 = e0;
      j0 = f0;
    } else {
      d1 = fminf(d1, e0);
    }
  }
  float sa = sqa[row];
  float v0 = sqrtf(fmaxf(sa + d0, 0.f));
  float v1 = sqrtf(fmaxf(sa + d1, 0.f));
  float ratio = v0 / v1;
  bool m = (ratio <= 0.8f);
  out[row]             = m ? ratio : 0.f;
  out[B + row * 2]     = (float)row;
  out[B + row * 2 + 1] = (float)j0;
  out[3 * B + row]     = m ? 1.f : 0.f;
}

extern "C" void kernel_launch(void* const* d_in, const int* in_sizes, int n_in,
                              void* d_out, int out_size, void* d_ws, size_t ws_size,
                              hipStream_t stream) {
  const float* d1 = (const float*)d_in[0];
  const float* d2 = (const float*)d_in[1];
  const int B = in_sizes[0] / D_;    // 16384

  float* ws   = (float*)d_ws;
  float* sqa  = ws;                       // [0, B)
  float* sqb  = ws + B;                   // [B, 2B)
  float* p_d0 = ws + 2 * B;               // [2B, 10B)
  float* p_d1 = ws + 10 * B;              // [10B, 18B)
  int*   p_j0 = (int*)(ws + 18 * B);      // [18B, 26B)
  _Float16* Ahi  = (_Float16*)(ws + 26 * B);
  _Float16* Alo  = Ahi + (size_t)B * D_;
  _Float16* BhiP = Alo + (size_t)B * D_;
  _Float16* BloP = BhiP + (size_t)B * D_;

  // norms
  int nthreads = 2 * B * 64;
  norms_kernel<<<(nthreads + 255) / 256, 256, 0, stream>>>(d1, d2, sqa, B);

  // f32 -> f16 hi/lo planes (A row-major; B fragment-packed, scaled by -2)
  int ngroups = 2 * B * 16;
  convert_kernel<<<(ngroups + 255) / 256, 256, 0, stream>>>(d1, d2, Ahi, Alo, BhiP, BloP, B);

  // main MFMA kernel: 2-wave blocks, 32 KiB dynamic LDS, 4 independent blocks/CU
  hipFuncSetAttribute((const void*)nn_mfma,
                      hipFuncAttributeMaxDynamicSharedMemorySize, 32768);
  nn_mfma<<<(B / BM_) * CS_, 128, 32768, stream>>>(Ahi, Alo, BhiP, BloP, sqb,
                                                   p_d0, p_d1, p_j0, B);

  // final merge + outputs
  nn_final<<<(B + 255) / 256, 256, 0, stream>>>(sqa, p_d0, p_d1, p_j0, (float*)d_out, B);
}

// Round 18
// 175.412 us; speedup vs baseline: 1.1494x; 1.1494x over previous
//
#include <hip/hip_runtime.h>
#include <math.h>
#include <float.h>
#include <stdint.h>

// NearestNeighborRatio: desc1/desc2 (B=16384, D=128) f32.
// d2(i,j) = |a_i|^2 + |b_j|^2 - 2 a_i.b_j; per-row top-2, ratio = sqrt(d0/d1), mask = ratio<=0.8.
// f16 hi/lo split (x = hi + lo): dot via 3 MFMAs (hh + hl + lh) in fp32 acc.
// v18: v12 + counted-vmcnt pipeline (T3/T4). 3-buffer LDS rotation (48KB), raw s_barrier,
//      s_waitcnt vmcnt(4) per iter (tile t+2's loads fly across the barrier; never drain
//      to 0 in the loop). sqb strip staged once into LDS (8KB) so the vmcnt FIFO holds
//      ONLY stage loads -> count-4 arithmetic exact. Register-neutral vs v12.
// Out (flat f32): [0,B) match_dists ; [B,3B) matches_idxs as floats ; [3B,4B) mask 0/1.

typedef __attribute__((ext_vector_type(4))) float     f32x4;
typedef __attribute__((ext_vector_type(8))) _Float16  half8;

#define D_     128
#define BM_    256   // rows per block (4 waves x 64)
#define BN_    32    // cols per iter (= one packed tile)
#define CS_    8     // column splits
#define PARTS_ 8     // partials per row = CS_
// LDS map: buf0 0, buf1 16384, buf2 32768, sq_lds 49152 (2048 f32) -> 57344 total

__device__ __forceinline__ void gload_lds16(const void* g, void* l) {
  auto gp = (const __attribute__((address_space(1))) unsigned int*)(uintptr_t)g;
  auto lp = (__attribute__((address_space(3))) unsigned int*)(uintptr_t)l;
  __builtin_amdgcn_global_load_lds(gp, lp, 16, 0, 0);
}

__global__ void norms_kernel(const float* __restrict__ d1,
                             const float* __restrict__ d2,
                             float* __restrict__ sq, int B) {
  int gid  = blockIdx.x * blockDim.x + threadIdx.x;
  int wid  = gid >> 6;
  int lane = gid & 63;
  if (wid >= 2 * B) return;
  const float* src = (wid < B) ? (d1 + (size_t)wid * D_)
                               : (d2 + (size_t)(wid - B) * D_);
  float2 v = ((const float2*)src)[lane];
  float s = fmaf(v.x, v.x, v.y * v.y);
  #pragma unroll
  for (int off = 32; off > 0; off >>= 1) s += __shfl_down(s, off, 64);
  if (lane == 0) sq[wid] = s;
}

// A planes: row-major [B][128] f16 (unscaled).
// B planes: packed fragment order per 32-col tile, PRE-SCALED BY -2:
//   f16 offset = t*4096 + kk*1024 + nf*512 + g*128 + c15*8
//   holds -2*desc2[t*32 + nf*16 + c15][kk*32 + g*8 .. +8]
__global__ void convert_kernel(const float* __restrict__ d1, const float* __restrict__ d2,
                               _Float16* __restrict__ Ahi, _Float16* __restrict__ Alo,
                               _Float16* __restrict__ BhiP, _Float16* __restrict__ BloP,
                               int B) {
  int i = blockIdx.x * blockDim.x + threadIdx.x;
  int total = B * 16;                       // 8-elem groups per matrix
  if (i >= 2 * total) return;
  bool isB = i >= total;
  int j    = isB ? i - total : i;
  int desc = j >> 4;
  int seg  = j & 15;                        // 8-f32 group within the row
  const float* src = (isB ? d2 : d1) + (size_t)desc * D_ + seg * 8;
  float4 v0 = *(const float4*)(src);
  float4 v1 = *(const float4*)(src + 4);
  half8 hv, lv;
  float e[8] = {v0.x, v0.y, v0.z, v0.w, v1.x, v1.y, v1.z, v1.w};
  #pragma unroll
  for (int q = 0; q < 8; ++q) {
    _Float16 h = (_Float16)e[q];
    _Float16 l = (_Float16)(e[q] - (float)h);
    if (isB) { h = (_Float16)(-2.0f) * h; l = (_Float16)(-2.0f) * l; }
    hv[q] = h; lv[q] = l;
  }
  if (!isB) {
    *(half8*)(Ahi + (size_t)desc * D_ + seg * 8) = hv;
    *(half8*)(Alo + (size_t)desc * D_ + seg * 8) = lv;
  } else {
    int t   = desc >> 5, cloc = desc & 31;
    int nf  = cloc >> 4, c15  = cloc & 15;
    int kk  = seg >> 2,  gq   = seg & 3;
    size_t off = (size_t)t * 4096 + kk * 1024 + nf * 512 + gq * 128 + c15 * 8;
    *(half8*)(BhiP + off) = hv;
    *(half8*)(BloP + off) = lv;
  }
}

__global__ __launch_bounds__(256, 2)
void nn_mfma(const _Float16* __restrict__ Ahi, const _Float16* __restrict__ Alo,
             const _Float16* __restrict__ BhiP, const _Float16* __restrict__ BloP,
             const float* __restrict__ sqb,
             float* __restrict__ p_d0, float* __restrict__ p_d1,
             int* __restrict__ p_j0, int B) {
  extern __shared__ char smem[];
  float* sq_lds = (float*)(smem + 49152);
  const int tid  = threadIdx.x;
  const int lane = tid & 63;
  const int wid  = tid >> 6;       // wave row-group: rows wid*64..wid*64+63
  const int l15  = lane & 15;
  const int g    = lane >> 4;

  const int nrb   = B / BM_;            // 64
  const int rb    = blockIdx.x % nrb;
  const int cspl  = blockIdx.x / nrb;
  const int i0    = rb * BM_;
  const int niter = (B / CS_) / BN_;    // 64
  const int tile0 = cspl * niter;

  // ---- A fragments -> registers, once (64 rows per wave: mf=0..3) ----
  half8 ah[4][4], al[4][4];
  #pragma unroll
  for (int mf = 0; mf < 4; ++mf) {
    int row = i0 + wid * 64 + mf * 16 + l15;
    const _Float16* pa = Ahi + (size_t)row * D_ + g * 8;
    const _Float16* pl = Alo + (size_t)row * D_ + g * 8;
    #pragma unroll
    for (int kk = 0; kk < 4; ++kk) {
      ah[mf][kk] = *(const half8*)(pa + kk * 32);
      al[mf][kk] = *(const half8*)(pl + kk * 32);
    }
  }

  // ---- sq strip -> LDS once (2048 f32 = 8KB) ----
  {
    const float* sqs = sqb + cspl * 2048;
    #pragma unroll
    for (int e = 0; e < 2; ++e) {
      int idx = tid + e * 256;                  // float4 index 0..511
      float4 v = ((const float4*)sqs)[idx];
      ((float4*)sq_lds)[idx] = v;
    }
  }

  // ---- staging: 16 x 1KB chunks per tile; wave wid stages 4 (one gload each) ----
  const _Float16* srcW = ((wid < 2) ? BhiP : BloP)
                       + (size_t)tile0 * 4096 + (wid & 1) * 2048 + lane * 8;
  char* ldsW = smem + (wid >> 1) * 8192 + (wid & 1) * 4096;   // + bufbase
  auto stage = [&](int bufbase, int it) {
    const _Float16* s = srcW + (size_t)it * 4096;
    char* l = ldsW + bufbase;
    #pragma unroll
    for (int e = 0; e < 4; ++e) gload_lds16(s + e * 512, l + e * 1024);
  };

  float best0[16], best1[16]; int bj[16];
  #pragma unroll
  for (int s = 0; s < 16; ++s) { best0[s] = FLT_MAX; best1[s] = FLT_MAX; bj[s] = 0x7fffffff; }

  const int colg0 = tile0 * BN_ + l15;

  // ---- prologue: stage tiles 0,1; drain tile0 (per-wave 4 newest stay in flight) ----
  stage(0, 0);
  stage(16384, 1);
  asm volatile("s_waitcnt vmcnt(4)" ::: "memory");
  asm volatile("s_waitcnt lgkmcnt(0)" ::: "memory");   // sq_lds writes visible
  __builtin_amdgcn_s_barrier();
  asm volatile("" ::: "memory");

  float sjc0 = sq_lds[l15];
  float sjc1 = sq_lds[16 + l15];

  int bcur = 0, bstage = 32768;
  for (int it = 0; it < niter; ++it) {
    // issue tile t+2 into the rotation buffer (its readers finished at t-1, barrier-ordered)
    if (it + 2 < niter) stage(bstage, it + 2);
    // prefetch next iter's sj from LDS (lgkm only — vmcnt FIFO stays pure stage loads)
    float sjn0 = 0.f, sjn1 = 0.f;
    if (it + 1 < niter) {
      sjn0 = sq_lds[(it + 1) * 32 + l15];
      sjn1 = sq_lds[(it + 1) * 32 + 16 + l15];
    }

    f32x4 acc[4][2];
    __builtin_amdgcn_s_setprio(1);
    #pragma unroll
    for (int kk = 0; kk < 4; ++kk) {
      half8 bh[2], bl[2];
      #pragma unroll
      for (int nf = 0; nf < 2; ++nf) {
        bh[nf] = *(const half8*)(smem + bcur + kk * 2048 + nf * 1024 + lane * 16);
        bl[nf] = *(const half8*)(smem + bcur + 8192 + kk * 2048 + nf * 1024 + lane * 16);
      }
      // term hh (C-init with sj at kk==0)
      #pragma unroll
      for (int mf = 0; mf < 4; ++mf)
        #pragma unroll
        for (int nf = 0; nf < 2; ++nf) {
          if (kk == 0) {
            float sj = nf ? sjc1 : sjc0;
            f32x4 c0 = {sj, sj, sj, sj};
            acc[mf][nf] = __builtin_amdgcn_mfma_f32_16x16x32_f16(ah[mf][0], bh[nf], c0, 0, 0, 0);
          } else {
            acc[mf][nf] = __builtin_amdgcn_mfma_f32_16x16x32_f16(ah[mf][kk], bh[nf], acc[mf][nf], 0, 0, 0);
          }
        }
      // term hl
      #pragma unroll
      for (int mf = 0; mf < 4; ++mf)
        #pragma unroll
        for (int nf = 0; nf < 2; ++nf)
          acc[mf][nf] = __builtin_amdgcn_mfma_f32_16x16x32_f16(ah[mf][kk], bl[nf], acc[mf][nf], 0, 0, 0);
      // term lh
      #pragma unroll
      for (int mf = 0; mf < 4; ++mf)
        #pragma unroll
        for (int nf = 0; nf < 2; ++nf)
          acc[mf][nf] = __builtin_amdgcn_mfma_f32_16x16x32_f16(al[mf][kk], bh[nf], acc[mf][nf], 0, 0, 0);
    }
    __builtin_amdgcn_s_setprio(0);

    // ---- top-2 fold (fmed3, 4 VALU/elem); acc[r] = sqb[j] - 2*dot already ----
    // C/D layout: col = lane&15, row = (lane>>4)*4 + reg
    #pragma unroll
    for (int nf = 0; nf < 2; ++nf) {
      int colg = colg0 + it * BN_ + nf * 16;
      #pragma unroll
      for (int mf = 0; mf < 4; ++mf)
        #pragma unroll
        for (int r = 0; r < 4; ++r) {
          int s = mf * 4 + r;
          float t = acc[mf][nf][r];
          best1[s] = __builtin_amdgcn_fmed3f(t, best0[s], best1[s]);
          bool lt0 = t < best0[s];
          best0[s] = fminf(t, best0[s]);
          bj[s]    = lt0 ? colg : bj[s];
        }
    }

    // ---- counted drain: only tile t+1's 4 per-wave loads; t+2's stay in flight ----
    if (it + 2 < niter) asm volatile("s_waitcnt vmcnt(4)" ::: "memory");
    else                asm volatile("s_waitcnt vmcnt(0)" ::: "memory");
    __builtin_amdgcn_s_barrier();
    asm volatile("" ::: "memory");

    sjc0 = sjn0; sjc1 = sjn1;
    bcur   = (bcur   == 32768) ? 0 : bcur   + 16384;
    bstage = (bstage == 32768) ? 0 : bstage + 16384;
  }

  // ---- merge across the 16 col-lanes (same g), index tie-break ----
  #pragma unroll
  for (int off = 1; off < 16; off <<= 1) {
    #pragma unroll
    for (int s = 0; s < 16; ++s) {
      float e0 = __shfl_xor(best0[s], off, 64);
      float e1 = __shfl_xor(best1[s], off, 64);
      int   f0 = __shfl_xor(bj[s],    off, 64);
      if (e0 < best0[s] || (e0 == best0[s] && f0 < bj[s])) {
        best1[s] = fminf(best0[s], e1);
        best0[s] = e0;
        bj[s]    = f0;
      } else {
        best1[s] = fminf(best1[s], e0);
      }
    }
  }

  if (l15 == 0) {
    #pragma unroll
    for (int s = 0; s < 16; ++s) {
      int mf = s >> 2, r = s & 3;
      int row = i0 + wid * 64 + mf * 16 + g * 4 + r;
      p_d0[row * PARTS_ + cspl] = best0[s];
      p_d1[row * PARTS_ + cspl] = best1[s];
      p_j0[row * PARTS_ + cspl] = bj[s];
    }
  }
}

__global__ void nn_final(const float* __restrict__ sqa,
                         const float* __restrict__ p_d0,
                         const float* __restrict__ p_d1,
                         const int* __restrict__ p_j0,
                         float* __restrict__ out, int B) {
  int row = blockIdx.x * blockDim.x + threadIdx.x;
  if (row >= B) return;
  float d0 = FLT_MAX, d1 = FLT_MAX;
  int j0 = 0x7fffffff;
  for (int cs = 0; cs < PARTS_; ++cs) {
    float e0 = p_d0[row * PARTS_ + cs];
    float e1 = p_d1[row * PARTS_ + cs];
    int   f0 = p_j0[row * PARTS_ + cs];
    if (e0 < d0 || (e0 == d0 && f0 < j0)) {
      d1 = fminf(d0, e1);
      d0 = e0;
      j0 = f0;
    } else {
      d1 = fminf(d1, e0);
    }
  }
  float sa = sqa[row];
  float v0 = sqrtf(fmaxf(sa + d0, 0.f));
  float v1 = sqrtf(fmaxf(sa + d1, 0.f));
  float ratio = v0 / v1;
  bool m = (ratio <= 0.8f);
  out[row]             = m ? ratio : 0.f;
  out[B + row * 2]     = (float)row;
  out[B + row * 2 + 1] = (float)j0;
  out[3 * B + row]     = m ? 1.f : 0.f;
}

extern "C" void kernel_launch(void* const* d_in, const int* in_sizes, int n_in,
                              void* d_out, int out_size, void* d_ws, size_t ws_size,
                              hipStream_t stream) {
  const float* d1 = (const float*)d_in[0];
  const float* d2 = (const float*)d_in[1];
  const int B = in_sizes[0] / D_;    // 16384

  float* ws   = (float*)d_ws;
  float* sqa  = ws;                       // [0, B)
  float* sqb  = ws + B;                   // [B, 2B)
  float* p_d0 = ws + 2 * B;               // [2B, 10B)
  float* p_d1 = ws + 10 * B;              // [10B, 18B)
  int*   p_j0 = (int*)(ws + 18 * B);      // [18B, 26B)
  _Float16* Ahi  = (_Float16*)(ws + 26 * B);
  _Float16* Alo  = Ahi + (size_t)B * D_;
  _Float16* BhiP = Alo + (size_t)B * D_;
  _Float16* BloP = BhiP + (size_t)B * D_;

  // norms
  int nthreads = 2 * B * 64;
  norms_kernel<<<(nthreads + 255) / 256, 256, 0, stream>>>(d1, d2, sqa, B);

  // f32 -> f16 hi/lo planes (A row-major; B fragment-packed, scaled by -2)
  int ngroups = 2 * B * 16;
  convert_kernel<<<(ngroups + 255) / 256, 256, 0, stream>>>(d1, d2, Ahi, Alo, BhiP, BloP, B);

  // main MFMA kernel: 56 KiB dynamic LDS (3 bufs + sq strip), 2 blocks/CU
  hipFuncSetAttribute((const void*)nn_mfma,
                      hipFuncAttributeMaxDynamicSharedMemorySize, 57344);
  nn_mfma<<<(B / BM_) * CS_, 256, 57344, stream>>>(Ahi, Alo, BhiP, BloP, sqb,
                                                   p_d0, p_d1, p_j0, B);

  // final merge + outputs
  nn_final<<<(B + 255) / 256, 256, 0, stream>>>(sqa, p_d0, p_d1, p_j0, (float*)d_out, B);
}

// Round 19
// 173.867 us; speedup vs baseline: 1.1597x; 1.0089x over previous
//
#include <hip/hip_runtime.h>
#include <math.h>
#include <float.h>
#include <stdint.h>

// NearestNeighborRatio: desc1/desc2 (B=16384, D=128) f32.
// d2(i,j) = |a_i|^2 + |b_j|^2 - 2 a_i.b_j; per-row top-2, ratio = sqrt(d0/d1), mask = ratio<=0.8.
// f16 hi/lo split (x = hi + lo): dot via 3 MFMAs (hh + hl + lh) in fp32 acc.
// v19: v18 + 2-tile barrier period (4 LDS slots, one vmcnt(0)+s_barrier per 2 tiles ->
//      barrier events halved, stage loads get a full period to land) + norms fused
//      into convert (one less 16MB-read kernel).
// Out (flat f32): [0,B) match_dists ; [B,3B) matches_idxs as floats ; [3B,4B) mask 0/1.

typedef __attribute__((ext_vector_type(4))) float     f32x4;
typedef __attribute__((ext_vector_type(8))) _Float16  half8;

#define D_     128
#define BM_    256   // rows per block (4 waves x 64)
#define BN_    32    // cols per tile
#define CS_    8     // column splits
#define PARTS_ 8     // partials per row = CS_
// LDS map: tile slots 0/16K/32K/48K; sq_lds at 65536 (2048 f32) -> 73728 total

__device__ __forceinline__ void gload_lds16(const void* g, void* l) {
  auto gp = (const __attribute__((address_space(1))) unsigned int*)(uintptr_t)g;
  auto lp = (__attribute__((address_space(3))) unsigned int*)(uintptr_t)l;
  __builtin_amdgcn_global_load_lds(gp, lp, 16, 0, 0);
}

// A planes: row-major [B][128] f16 (unscaled).
// B planes: packed fragment order per 32-col tile, PRE-SCALED BY -2:
//   f16 offset = t*4096 + kk*1024 + nf*512 + g*128 + c15*8
//   holds -2*desc2[t*32 + nf*16 + c15][kk*32 + g*8 .. +8]
// Also computes row norms: sq[desc] (desc1) / sq[B+desc] (desc2) via 16-lane shfl reduce.
__global__ void convert_kernel(const float* __restrict__ d1, const float* __restrict__ d2,
                               _Float16* __restrict__ Ahi, _Float16* __restrict__ Alo,
                               _Float16* __restrict__ BhiP, _Float16* __restrict__ BloP,
                               float* __restrict__ sq, int B) {
  int i = blockIdx.x * blockDim.x + threadIdx.x;
  int total = B * 16;                       // 8-elem groups per matrix
  if (i >= 2 * total) return;
  bool isB = i >= total;
  int j    = isB ? i - total : i;
  int desc = j >> 4;
  int seg  = j & 15;                        // 8-f32 group within the row
  const float* src = (isB ? d2 : d1) + (size_t)desc * D_ + seg * 8;
  float4 v0 = *(const float4*)(src);
  float4 v1 = *(const float4*)(src + 4);
  half8 hv, lv;
  float e[8] = {v0.x, v0.y, v0.z, v0.w, v1.x, v1.y, v1.z, v1.w};
  float ss = 0.f;
  #pragma unroll
  for (int q = 0; q < 8; ++q) {
    ss = fmaf(e[q], e[q], ss);
    _Float16 h = (_Float16)e[q];
    _Float16 l = (_Float16)(e[q] - (float)h);
    if (isB) { h = (_Float16)(-2.0f) * h; l = (_Float16)(-2.0f) * l; }
    hv[q] = h; lv[q] = l;
  }
  // 16-lane reduce (groups of 16 aligned within the wave)
  #pragma unroll
  for (int off = 8; off > 0; off >>= 1) ss += __shfl_xor(ss, off, 64);
  if (seg == 0) sq[(isB ? B : 0) + desc] = ss;

  if (!isB) {
    *(half8*)(Ahi + (size_t)desc * D_ + seg * 8) = hv;
    *(half8*)(Alo + (size_t)desc * D_ + seg * 8) = lv;
  } else {
    int t   = desc >> 5, cloc = desc & 31;
    int nf  = cloc >> 4, c15  = cloc & 15;
    int kk  = seg >> 2,  gq   = seg & 3;
    size_t off = (size_t)t * 4096 + kk * 1024 + nf * 512 + gq * 128 + c15 * 8;
    *(half8*)(BhiP + off) = hv;
    *(half8*)(BloP + off) = lv;
  }
}

__global__ __launch_bounds__(256, 2)
void nn_mfma(const _Float16* __restrict__ Ahi, const _Float16* __restrict__ Alo,
             const _Float16* __restrict__ BhiP, const _Float16* __restrict__ BloP,
             const float* __restrict__ sqb,
             float* __restrict__ p_d0, float* __restrict__ p_d1,
             int* __restrict__ p_j0, int B) {
  extern __shared__ char smem[];
  float* sq_lds = (float*)(smem + 65536);
  const int tid  = threadIdx.x;
  const int lane = tid & 63;
  const int wid  = tid >> 6;       // wave row-group: rows wid*64..wid*64+63
  const int l15  = lane & 15;
  const int g    = lane >> 4;

  const int nrb   = B / BM_;            // 64
  const int rb    = blockIdx.x % nrb;
  const int cspl  = blockIdx.x / nrb;
  const int i0    = rb * BM_;
  const int ntile = (B / CS_) / BN_;    // 64 tiles -> 32 periods
  const int tile0 = cspl * ntile;

  // ---- A fragments -> registers, once (64 rows per wave: mf=0..3) ----
  half8 ah[4][4], al[4][4];
  #pragma unroll
  for (int mf = 0; mf < 4; ++mf) {
    int row = i0 + wid * 64 + mf * 16 + l15;
    const _Float16* pa = Ahi + (size_t)row * D_ + g * 8;
    const _Float16* pl = Alo + (size_t)row * D_ + g * 8;
    #pragma unroll
    for (int kk = 0; kk < 4; ++kk) {
      ah[mf][kk] = *(const half8*)(pa + kk * 32);
      al[mf][kk] = *(const half8*)(pl + kk * 32);
    }
  }

  // ---- sq strip -> LDS once (2048 f32 = 8KB) ----
  {
    const float* sqs = sqb + cspl * 2048;
    #pragma unroll
    for (int e = 0; e < 2; ++e) {
      int idx = tid + e * 256;                  // float4 index 0..511
      float4 v = ((const float4*)sqs)[idx];
      ((float4*)sq_lds)[idx] = v;
    }
  }

  // ---- staging: 16 x 1KB chunks per tile; wave wid stages 4 (one gload each) ----
  const _Float16* srcW = ((wid < 2) ? BhiP : BloP)
                       + (size_t)tile0 * 4096 + (wid & 1) * 2048 + lane * 8;
  char* ldsW = smem + (wid >> 1) * 8192 + (wid & 1) * 4096;   // + slotbase
  auto stage = [&](int slotbase, int t) {
    const _Float16* s = srcW + (size_t)t * 4096;
    char* l = ldsW + slotbase;
    #pragma unroll
    for (int e = 0; e < 4; ++e) gload_lds16(s + e * 512, l + e * 1024);
  };

  float best0[16], best1[16]; int bj[16];
  #pragma unroll
  for (int s = 0; s < 16; ++s) { best0[s] = FLT_MAX; best1[s] = FLT_MAX; bj[s] = 0x7fffffff; }

  const int colg0 = tile0 * BN_ + l15;

  // ---- compute one 32-col tile from LDS slot `sb` ----
  auto tilecomp = [&](int t, int sb) {
    float sjc0 = sq_lds[t * 32 + l15];
    float sjc1 = sq_lds[t * 32 + 16 + l15];
    f32x4 acc[4][2];
    __builtin_amdgcn_s_setprio(1);
    #pragma unroll
    for (int kk = 0; kk < 4; ++kk) {
      half8 bh[2], bl[2];
      #pragma unroll
      for (int nf = 0; nf < 2; ++nf) {
        bh[nf] = *(const half8*)(smem + sb + kk * 2048 + nf * 1024 + lane * 16);
        bl[nf] = *(const half8*)(smem + sb + 8192 + kk * 2048 + nf * 1024 + lane * 16);
      }
      #pragma unroll
      for (int mf = 0; mf < 4; ++mf)
        #pragma unroll
        for (int nf = 0; nf < 2; ++nf) {
          if (kk == 0) {
            float sj = nf ? sjc1 : sjc0;
            f32x4 c0 = {sj, sj, sj, sj};
            acc[mf][nf] = __builtin_amdgcn_mfma_f32_16x16x32_f16(ah[mf][0], bh[nf], c0, 0, 0, 0);
          } else {
            acc[mf][nf] = __builtin_amdgcn_mfma_f32_16x16x32_f16(ah[mf][kk], bh[nf], acc[mf][nf], 0, 0, 0);
          }
        }
      #pragma unroll
      for (int mf = 0; mf < 4; ++mf)
        #pragma unroll
        for (int nf = 0; nf < 2; ++nf)
          acc[mf][nf] = __builtin_amdgcn_mfma_f32_16x16x32_f16(ah[mf][kk], bl[nf], acc[mf][nf], 0, 0, 0);
      #pragma unroll
      for (int mf = 0; mf < 4; ++mf)
        #pragma unroll
        for (int nf = 0; nf < 2; ++nf)
          acc[mf][nf] = __builtin_amdgcn_mfma_f32_16x16x32_f16(al[mf][kk], bh[nf], acc[mf][nf], 0, 0, 0);
    }
    __builtin_amdgcn_s_setprio(0);

    // top-2 fold (fmed3); acc = sqb[j] - 2*dot. C/D: col=lane&15, row=(lane>>4)*4+reg
    #pragma unroll
    for (int nf = 0; nf < 2; ++nf) {
      int colg = colg0 + t * BN_ + nf * 16;
      #pragma unroll
      for (int mf = 0; mf < 4; ++mf)
        #pragma unroll
        for (int r = 0; r < 4; ++r) {
          int s = mf * 4 + r;
          float v = acc[mf][nf][r];
          best1[s] = __builtin_amdgcn_fmed3f(v, best0[s], best1[s]);
          bool lt0 = v < best0[s];
          best0[s] = fminf(v, best0[s]);
          bj[s]    = lt0 ? colg : bj[s];
        }
    }
  };

  // ---- prologue: stage tiles 0,1 into slots 0,1 ----
  stage(0, 0);
  stage(16384, 1);
  asm volatile("s_waitcnt vmcnt(0)" ::: "memory");
  asm volatile("s_waitcnt lgkmcnt(0)" ::: "memory");   // sq_lds writes visible
  __builtin_amdgcn_s_barrier();
  asm volatile("" ::: "memory");

  const int nper = ntile / 2;   // 32 periods
  for (int p = 0; p < nper; ++p) {
    const int sbcur = (p & 1) * 32768;
    // stage next pair into the other slot pair (readers finished last period, barrier-ordered)
    if (p + 1 < nper) {
      stage(sbcur ^ 32768, 2 * p + 2);
      stage((sbcur ^ 32768) + 16384, 2 * p + 3);
    }

    tilecomp(2 * p,     sbcur);
    tilecomp(2 * p + 1, sbcur + 16384);

    // one drain+barrier per 2 tiles; the 8 stage loads had a full period to land
    asm volatile("s_waitcnt vmcnt(0)" ::: "memory");
    __builtin_amdgcn_s_barrier();
    asm volatile("" ::: "memory");
  }

  // ---- merge across the 16 col-lanes (same g), index tie-break ----
  #pragma unroll
  for (int off = 1; off < 16; off <<= 1) {
    #pragma unroll
    for (int s = 0; s < 16; ++s) {
      float e0 = __shfl_xor(best0[s], off, 64);
      float e1 = __shfl_xor(best1[s], off, 64);
      int   f0 = __shfl_xor(bj[s],    off, 64);
      if (e0 < best0[s] || (e0 == best0[s] && f0 < bj[s])) {
        best1[s] = fminf(best0[s], e1);
        best0[s] = e0;
        bj[s]    = f0;
      } else {
        best1[s] = fminf(best1[s], e0);
      }
    }
  }

  if (l15 == 0) {
    #pragma unroll
    for (int s = 0; s < 16; ++s) {
      int mf = s >> 2, r = s & 3;
      int row = i0 + wid * 64 + mf * 16 + g * 4 + r;
      p_d0[row * PARTS_ + cspl] = best0[s];
      p_d1[row * PARTS_ + cspl] = best1[s];
      p_j0[row * PARTS_ + cspl] = bj[s];
    }
  }
}

__global__ void nn_final(const float* __restrict__ sqa,
                         const float* __restrict__ p_d0,
                         const float* __restrict__ p_d1,
                         const int* __restrict__ p_j0,
                         float* __restrict__ out, int B) {
  int row = blockIdx.x * blockDim.x + threadIdx.x;
  if (row >= B) return;
  float d0 = FLT_MAX, d1 = FLT_MAX;
  int j0 = 0x7fffffff;
  for (int cs = 0; cs < PARTS_; ++cs) {
    float e0 = p_d0[row * PARTS_ + cs];
    float e1 = p_d1[row * PARTS_ + cs];
    int   f0 = p_j0[row * PARTS_ + cs];
    if (e0 < d0 || (e0 == d0 && f0 < j0)) {
      d1 = fminf(d0, e1);
      d0 = e0;
      j0 = f0;
    } else {
      d1 = fminf(d1, e0);
    }
  }
  float sa = sqa[row];
  float v0 = sqrtf(fmaxf(sa + d0, 0.f));
  float v1 = sqrtf(fmaxf(sa + d1, 0.f));
  float ratio = v0 / v1;
  bool m = (ratio <= 0.8f);
  out[row]             = m ? ratio : 0.f;
  out[B + row * 2]     = (float)row;
  out[B + row * 2 + 1] = (float)j0;
  out[3 * B + row]     = m ? 1.f : 0.f;
}

extern "C" void kernel_launch(void* const* d_in, const int* in_sizes, int n_in,
                              void* d_out, int out_size, void* d_ws, size_t ws_size,
                              hipStream_t stream) {
  const float* d1 = (const float*)d_in[0];
  const float* d2 = (const float*)d_in[1];
  const int B = in_sizes[0] / D_;    // 16384

  float* ws   = (float*)d_ws;
  float* sqa  = ws;                       // [0, B)
  float* sqb  = ws + B;                   // [B, 2B)
  float* p_d0 = ws + 2 * B;               // [2B, 10B)
  float* p_d1 = ws + 10 * B;              // [10B, 18B)
  int*   p_j0 = (int*)(ws + 18 * B);      // [18B, 26B)
  _Float16* Ahi  = (_Float16*)(ws + 26 * B);
  _Float16* Alo  = Ahi + (size_t)B * D_;
  _Float16* BhiP = Alo + (size_t)B * D_;
  _Float16* BloP = BhiP + (size_t)B * D_;

  // fused convert + norms (A row-major; B fragment-packed, scaled by -2; sq norms)
  int ngroups = 2 * B * 16;
  convert_kernel<<<(ngroups + 255) / 256, 256, 0, stream>>>(d1, d2, Ahi, Alo, BhiP, BloP, sqa, B);

  // main MFMA kernel: 72 KiB dynamic LDS (4 tile slots + sq strip), 2 blocks/CU
  hipFuncSetAttribute((const void*)nn_mfma,
                      hipFuncAttributeMaxDynamicSharedMemorySize, 73728);
  nn_mfma<<<(B / BM_) * CS_, 256, 73728, stream>>>(Ahi, Alo, BhiP, BloP, sqb,
                                                   p_d0, p_d1, p_j0, B);

  // final merge + outputs
  nn_final<<<(B + 255) / 256, 256, 0, stream>>>(sqa, p_d0, p_d1, p_j0, (float*)d_out, B);
}